// Round 1
// baseline (678.213 us; speedup 1.0000x reference)
//
#include <hip/hip_runtime.h>
#include <hip/hip_bf16.h>
#include <math.h>

#define HN 39
#define WN 39
#define NBATCH 128
#define NPIX (HN * WN)          // 1521
#define NNODE (NBATCH * WN)     // 4992
#define E_RAW 200064
#define E_TOT (E_RAW + NNODE)   // 205056
#define F1 512
#define F2 64

static __device__ __forceinline__ float nan0(float x) { return (x == x) ? x : 0.f; }
static __device__ __forceinline__ float sigmoid_f(float x) { return 1.f / (1.f + __expf(-x)); }
static __device__ __forceinline__ float tanh_f(float x) {
    float e = __expf(2.f * x);
    return 1.f - 2.f / (e + 1.f);   // robust: +/-inf -> +/-1
}

#define BN_RSQ 0.99999500003749969f   // 1/sqrt(1+1e-5)

// ---------------------------------------------------------------------------
// K1: fused nan-clean + conv1(1x1)+BN+ReLU + conv2(3x3)+BN + GRU input proj
// grid 128 blocks (one per image), 256 threads
// ---------------------------------------------------------------------------
__global__ __launch_bounds__(256) void conv_kernel(
    const float* __restrict__ ve, const float* __restrict__ ac, const float* __restrict__ man,
    const float* __restrict__ c1w, const float* __restrict__ c1b,
    const float* __restrict__ bn1g, const float* __restrict__ bn1b,
    const float* __restrict__ c2w, const float* __restrict__ c2b,
    const float* __restrict__ bn2g, const float* __restrict__ bn2b,
    const float* __restrict__ wih, const float* __restrict__ bih,
    float* __restrict__ gi_out)      // (B, 1521, 3)
{
    __shared__ float y1[8][NPIX + 7];
    const int b = blockIdx.x;
    const int tid = threadIdx.x;

    // phase 1: conv1 (1x1) + bn + relu for all 8 channels
    for (int p = tid; p < NPIX; p += 256) {
        float m = nan0(man[b * NPIX + p]);
        float a = nan0(ac[b * NPIX + p]);
        float v = nan0(ve[b * NPIX + p]);
#pragma unroll
        for (int c = 0; c < 8; ++c) {
            float val = c1w[c * 3 + 0] * m + c1w[c * 3 + 1] * a + c1w[c * 3 + 2] * v + c1b[c];
            val = val * (bn1g[c] * BN_RSQ) + bn1b[c];
            y1[c][p] = fmaxf(val, 0.f);
        }
    }
    __syncthreads();

    // phase 2: conv2 (3x3 pad 1) + bn2, then gi = x2 . wih^T + bih
    for (int p = tid; p < NPIX; p += 256) {
        const int h = p / WN, w = p - h * WN;
        float acc[16];
#pragma unroll
        for (int o = 0; o < 16; ++o) acc[o] = 0.f;
        for (int c = 0; c < 8; ++c) {
#pragma unroll
            for (int dy = 0; dy < 3; ++dy) {
                const int hh = h + dy - 1;
                if (hh < 0 || hh >= HN) continue;
#pragma unroll
                for (int dx = 0; dx < 3; ++dx) {
                    const int ww = w + dx - 1;
                    if (ww < 0 || ww >= WN) continue;
                    const float yv = y1[c][hh * WN + ww];
#pragma unroll
                    for (int o = 0; o < 16; ++o)
                        acc[o] = fmaf(c2w[((o * 8 + c) * 3 + dy) * 3 + dx], yv, acc[o]);
                }
            }
        }
        float gi0 = bih[0], gi1 = bih[1], gi2 = bih[2];
#pragma unroll
        for (int o = 0; o < 16; ++o) {
            const float x2 = (acc[o] + c2b[o]) * (bn2g[o] * BN_RSQ) + bn2b[o];
            gi0 = fmaf(wih[0 * 16 + o], x2, gi0);
            gi1 = fmaf(wih[1 * 16 + o], x2, gi1);
            gi2 = fmaf(wih[2 * 16 + o], x2, gi2);
        }
        const int idx = (b * NPIX + p) * 3;
        gi_out[idx + 0] = gi0;
        gi_out[idx + 1] = gi1;
        gi_out[idx + 2] = gi2;
    }
}

// ---------------------------------------------------------------------------
// K2: GRU(16->1) over rows; one thread per (b,w) sequence
// ---------------------------------------------------------------------------
__global__ __launch_bounds__(256) void gru_kernel(
    const float* __restrict__ gi, const float* __restrict__ whh, const float* __restrict__ bhh,
    float* __restrict__ enc1)   // (B, 39, 39)
{
    const int idx = blockIdx.x * 256 + threadIdx.x;
    if (idx >= NNODE) return;
    const int b = idx / WN, w = idx - (idx / WN) * WN;
    const float wh0 = whh[0], wh1 = whh[1], wh2 = whh[2];
    const float bh0 = bhh[0], bh1 = bhh[1], bh2 = bhh[2];
    float h = 0.f;
    for (int t = 0; t < HN; ++t) {
        const float* g = gi + ((size_t)b * NPIX + t * WN + w) * 3;
        const float g0 = g[0], g1 = g[1], g2 = g[2];
        const float r = sigmoid_f(g0 + h * wh0 + bh0);
        const float z = sigmoid_f(g1 + h * wh1 + bh1);
        const float n = tanh_f(g2 + r * (h * wh2 + bh2));
        h = (1.f - z) * n + z * h;
        enc1[b * NPIX + t * WN + w] = h;
    }
}

// ---------------------------------------------------------------------------
// K3: build node features xn (N, 78) = [man*mask ; enc1*mask] transposed
// ---------------------------------------------------------------------------
__global__ __launch_bounds__(256) void xn_kernel(
    const float* __restrict__ man, const float* __restrict__ enc1,
    const float* __restrict__ maskv, float* __restrict__ xn)
{
    const int idx = blockIdx.x * 256 + threadIdx.x;
    if (idx >= NNODE * 78) return;
    const int n = idx / 78, k = idx - n * 78;
    const int b = n / WN, w = n - b * WN;
    const float mk = maskv[b * WN + w];
    float v;
    if (k < HN) v = nan0(man[b * NPIX + k * WN + w]);
    else        v = enc1[b * NPIX + (k - HN) * WN + w];
    xn[idx] = v * mk;
}

// ---------------------------------------------------------------------------
// K4: CSR build (histogram -> scan -> scatter)
// ---------------------------------------------------------------------------
__global__ __launch_bounds__(256) void edge_hist(const int* __restrict__ ei, int* __restrict__ counts)
{
    const int e = blockIdx.x * 256 + threadIdx.x;
    if (e >= E_TOT) return;
    const int d = (e < E_RAW) ? ei[E_RAW + e] : (e - E_RAW);
    atomicAdd(&counts[d], 1);
}

__global__ __launch_bounds__(256) void scan_kernel(const int* __restrict__ counts,
                                                   int* __restrict__ offsets, int* __restrict__ cursor)
{
    __shared__ int sums[256];
    const int tid = threadIdx.x;
    const int start = tid * 20;
    const int end = min(start + 20, NNODE);
    int s = 0;
    for (int i = start; i < end; ++i) s += counts[i];
    sums[tid] = s;
    __syncthreads();
    for (int off = 1; off < 256; off <<= 1) {
        int v = (tid >= off) ? sums[tid - off] : 0;
        __syncthreads();
        sums[tid] += v;
        __syncthreads();
    }
    int run = (tid == 0) ? 0 : sums[tid - 1];
    for (int i = start; i < end; ++i) {
        offsets[i] = run;
        cursor[i] = run;
        run += counts[i];
    }
    if (tid == 255) offsets[NNODE] = run;
}

__global__ __launch_bounds__(256) void edge_scatter(const int* __restrict__ ei,
                                                    int* __restrict__ cursor, int* __restrict__ srcs)
{
    const int e = blockIdx.x * 256 + threadIdx.x;
    if (e >= E_TOT) return;
    int s, d;
    if (e < E_RAW) { s = ei[e]; d = ei[E_RAW + e]; }
    else           { s = d = e - E_RAW; }
    const int pos = atomicAdd(&cursor[d], 1);
    srcs[pos] = s;
}

// ---------------------------------------------------------------------------
// K5: tiled f32 GEMM  Y = X (M,K) @ W(J,K)^T + b ; blockIdx.z selects (Wl,Yl)/(Wr,Yr)
// ---------------------------------------------------------------------------
template <int K>
__global__ __launch_bounds__(256) void gemm_kernel(
    const float* __restrict__ X,
    const float* __restrict__ Wl, const float* __restrict__ bl,
    const float* __restrict__ Wr, const float* __restrict__ br,
    float* __restrict__ Yl, float* __restrict__ Yr, int J)
{
    const float* __restrict__ W = blockIdx.z ? Wr : Wl;
    const float* __restrict__ bias = blockIdx.z ? br : bl;
    float* __restrict__ Y = blockIdx.z ? Yr : Yl;

    __shared__ __align__(16) float Xs[32][68];
    __shared__ __align__(16) float Ws[32][68];

    const int m0 = blockIdx.x * 64, j0 = blockIdx.y * 64;
    const int tid = threadIdx.x;
    const int ti = tid / 16, tj = tid & 15;
    const int lrow = tid >> 2;            // 0..63
    const int ks = (tid & 3) * 8;         // 0,8,16,24

    float acc[4][4];
#pragma unroll
    for (int i = 0; i < 4; ++i)
#pragma unroll
        for (int j = 0; j < 4; ++j) acc[i][j] = 0.f;

    for (int k0 = 0; k0 < K; k0 += 32) {
        const float* xp = X + (size_t)(m0 + lrow) * K + k0 + ks;
        const float* wp = W + (size_t)(j0 + lrow) * K + k0 + ks;
#pragma unroll
        for (int q = 0; q < 8; ++q) {
            const int k = k0 + ks + q;
            Xs[ks + q][lrow] = (k < K) ? xp[q] : 0.f;
            Ws[ks + q][lrow] = (k < K) ? wp[q] : 0.f;
        }
        __syncthreads();
#pragma unroll
        for (int kk = 0; kk < 32; ++kk) {
            const float4 xv = *(const float4*)&Xs[kk][ti * 4];
            const float4 wv = *(const float4*)&Ws[kk][tj * 4];
            acc[0][0] = fmaf(xv.x, wv.x, acc[0][0]);
            acc[0][1] = fmaf(xv.x, wv.y, acc[0][1]);
            acc[0][2] = fmaf(xv.x, wv.z, acc[0][2]);
            acc[0][3] = fmaf(xv.x, wv.w, acc[0][3]);
            acc[1][0] = fmaf(xv.y, wv.x, acc[1][0]);
            acc[1][1] = fmaf(xv.y, wv.y, acc[1][1]);
            acc[1][2] = fmaf(xv.y, wv.z, acc[1][2]);
            acc[1][3] = fmaf(xv.y, wv.w, acc[1][3]);
            acc[2][0] = fmaf(xv.z, wv.x, acc[2][0]);
            acc[2][1] = fmaf(xv.z, wv.y, acc[2][1]);
            acc[2][2] = fmaf(xv.z, wv.z, acc[2][2]);
            acc[2][3] = fmaf(xv.z, wv.w, acc[2][3]);
            acc[3][0] = fmaf(xv.w, wv.x, acc[3][0]);
            acc[3][1] = fmaf(xv.w, wv.y, acc[3][1]);
            acc[3][2] = fmaf(xv.w, wv.z, acc[3][2]);
            acc[3][3] = fmaf(xv.w, wv.w, acc[3][3]);
        }
        __syncthreads();
    }
#pragma unroll
    for (int i = 0; i < 4; ++i) {
        const int m = m0 + ti * 4 + i;
#pragma unroll
        for (int j = 0; j < 4; ++j) {
            const int jj = j0 + tj * 4 + j;
            Y[(size_t)m * J + jj] = acc[i][j] + bias[jj];
        }
    }
}

// ---------------------------------------------------------------------------
// K6: GATv2 layer 1 (8 heads x 64ch). One block (512 thr) per dst node;
// wave id == head. Online softmax over CSR edges, single gather per edge.
// ---------------------------------------------------------------------------
__global__ __launch_bounds__(512) void gat1_kernel(
    const float* __restrict__ xl, const float* __restrict__ xr,
    const float* __restrict__ att, const float* __restrict__ bias,
    const int* __restrict__ offsets, const int* __restrict__ srcs,
    float* __restrict__ h1)
{
    const int n = blockIdx.x;
    const int t = threadIdx.x;
    const float xrv = xr[(size_t)n * F1 + t];
    const float attv = att[t];
    const int base = offsets[n];
    const int deg = offsets[n + 1] - base;

    float m = -1e30f, l = 0.f, acc = 0.f;
    int s = srcs[base];
    for (int i = 0; i < deg; ++i) {
        const int s_cur = s;
        if (i + 1 < deg) s = srcs[base + i + 1];
        const float xlv = xl[(size_t)s_cur * F1 + t];
        float ev = xlv + xrv;
        ev = (ev > 0.f) ? ev : 0.2f * ev;
        float part = ev * attv;
#pragma unroll
        for (int o = 32; o >= 1; o >>= 1) part += __shfl_xor(part, o, 64);
        const float logit = part;
        const float m2 = fmaxf(m, logit);
        const float sc = __expf(m - m2);
        const float w = __expf(logit - m2);
        l = l * sc + w;
        acc = acc * sc + w * xlv;
        m = m2;
    }
    float out = acc / l + bias[t];
    out = (out > 0.f) ? out : expm1f(out);   // ELU
    h1[(size_t)n * F1 + t] = out;
}

// ---------------------------------------------------------------------------
// K7: GATv2 layer 2 (1 head x 64ch). One wave per dst node, 4 nodes/block.
// ---------------------------------------------------------------------------
__global__ __launch_bounds__(256) void gat2_kernel(
    const float* __restrict__ xl, const float* __restrict__ xr,
    const float* __restrict__ att, const float* __restrict__ bias,
    const int* __restrict__ offsets, const int* __restrict__ srcs,
    float* __restrict__ out)
{
    const int wave = threadIdx.x >> 6;
    const int lane = threadIdx.x & 63;
    const int n = blockIdx.x * 4 + wave;
    if (n >= NNODE) return;
    const float xrv = xr[(size_t)n * F2 + lane];
    const float attv = att[lane];
    const int base = offsets[n];
    const int deg = offsets[n + 1] - base;

    float m = -1e30f, l = 0.f, acc = 0.f;
    int s = srcs[base];
    for (int i = 0; i < deg; ++i) {
        const int s_cur = s;
        if (i + 1 < deg) s = srcs[base + i + 1];
        const float xlv = xl[(size_t)s_cur * F2 + lane];
        float ev = xlv + xrv;
        ev = (ev > 0.f) ? ev : 0.2f * ev;
        float part = ev * attv;
#pragma unroll
        for (int o = 32; o >= 1; o >>= 1) part += __shfl_xor(part, o, 64);
        const float logit = part;
        const float m2 = fmaxf(m, logit);
        const float sc = __expf(m - m2);
        const float w = __expf(logit - m2);
        l = l * sc + w;
        acc = acc * sc + w * xlv;
        m = m2;
    }
    out[(size_t)n * F2 + lane] = acc / l + bias[lane];
}

// ---------------------------------------------------------------------------
extern "C" void kernel_launch(void* const* d_in, const int* in_sizes, int n_in,
                              void* d_out, int out_size, void* d_ws, size_t ws_size,
                              hipStream_t stream)
{
    const int*   ei    = (const int*)d_in[0];
    const float* ve    = (const float*)d_in[1];
    const float* ac    = (const float*)d_in[2];
    const float* man   = (const float*)d_in[3];
    const float* maskv = (const float*)d_in[4];
    const float* c1w   = (const float*)d_in[6];
    const float* c1b   = (const float*)d_in[7];
    const float* bn1g  = (const float*)d_in[8];
    const float* bn1b  = (const float*)d_in[9];
    const float* c2w   = (const float*)d_in[10];
    const float* c2b   = (const float*)d_in[11];
    const float* bn2g  = (const float*)d_in[12];
    const float* bn2b  = (const float*)d_in[13];
    const float* wih   = (const float*)d_in[14];
    const float* whh   = (const float*)d_in[15];
    const float* bih   = (const float*)d_in[16];
    const float* bhh   = (const float*)d_in[17];
    const float* g1wl  = (const float*)d_in[18];
    const float* g1bl  = (const float*)d_in[19];
    const float* g1wr  = (const float*)d_in[20];
    const float* g1br  = (const float*)d_in[21];
    const float* g1att = (const float*)d_in[22];
    const float* g1bias= (const float*)d_in[23];
    const float* g2wl  = (const float*)d_in[24];
    const float* g2bl  = (const float*)d_in[25];
    const float* g2wr  = (const float*)d_in[26];
    const float* g2br  = (const float*)d_in[27];
    const float* g2att = (const float*)d_in[28];
    const float* g2bias= (const float*)d_in[29];
    float* outp = (float*)d_out;

    // workspace layout (floats)
    float* ws   = (float*)d_ws;
    float* gi   = ws;                       // 584064
    float* enc1 = gi   + 584064;            // 194688
    float* xn   = enc1 + 194688;            // 389376
    float* xl1  = xn   + 389376;            // 2555904
    float* xr1  = xl1  + 2555904;           // 2555904
    float* h1   = xr1  + 2555904;           // 2555904
    float* xl2  = h1   + 2555904;           // 319488
    float* xr2  = xl2  + 319488;            // 319488
    int* counts  = (int*)(xr2 + 319488);    // 4992
    int* offsets = counts + NNODE;          // 4993
    int* cursor  = offsets + NNODE + 1;     // 4992
    int* srcs    = cursor + NNODE;          // 205056

    hipMemsetAsync(counts, 0, NNODE * sizeof(int), stream);

    conv_kernel<<<NBATCH, 256, 0, stream>>>(ve, ac, man, c1w, c1b, bn1g, bn1b,
                                            c2w, c2b, bn2g, bn2b, wih, bih, gi);
    gru_kernel<<<(NNODE + 255) / 256, 256, 0, stream>>>(gi, whh, bhh, enc1);
    xn_kernel<<<(NNODE * 78 + 255) / 256, 256, 0, stream>>>(man, enc1, maskv, xn);

    edge_hist<<<(E_TOT + 255) / 256, 256, 0, stream>>>(ei, counts);
    scan_kernel<<<1, 256, 0, stream>>>(counts, offsets, cursor);
    edge_scatter<<<(E_TOT + 255) / 256, 256, 0, stream>>>(ei, cursor, srcs);

    gemm_kernel<78><<<dim3(NNODE / 64, F1 / 64, 2), 256, 0, stream>>>(
        xn, g1wl, g1bl, g1wr, g1br, xl1, xr1, F1);

    gat1_kernel<<<NNODE, 512, 0, stream>>>(xl1, xr1, g1att, g1bias, offsets, srcs, h1);

    gemm_kernel<512><<<dim3(NNODE / 64, F2 / 64, 2), 256, 0, stream>>>(
        h1, g2wl, g2bl, g2wr, g2br, xl2, xr2, F2);

    gat2_kernel<<<(NNODE + 3) / 4, 256, 0, stream>>>(xl2, xr2, g2att, g2bias, offsets, srcs, outp);
}

// Round 3
// 457.534 us; speedup vs baseline: 1.4823x; 1.4823x over previous
//
#include <hip/hip_runtime.h>
#include <hip/hip_bf16.h>
#include <math.h>

#define HN 39
#define WN 39
#define NBATCH 128
#define NPIX (HN * WN)          // 1521
#define NNODE (NBATCH * WN)     // 4992
#define E_RAW 200064
#define E_TOT (E_RAW + NNODE)   // 205056
#define F1 512
#define F2 64

static __device__ __forceinline__ float nan0(float x) { return (x == x) ? x : 0.f; }
static __device__ __forceinline__ float sigmoid_f(float x) { return 1.f / (1.f + __expf(-x)); }
static __device__ __forceinline__ float tanh_f(float x) {
    float e = __expf(2.f * x);
    return 1.f - 2.f / (e + 1.f);   // robust: +/-inf -> +/-1
}

#define BN_RSQ 0.99999500003749969f   // 1/sqrt(1+1e-5)

// ---------------------------------------------------------------------------
// K1: fused nan-clean + conv1(1x1)+BN+ReLU + conv2(3x3)+BN + GRU input proj
// ---------------------------------------------------------------------------
__global__ __launch_bounds__(256) void conv_kernel(
    const float* __restrict__ ve, const float* __restrict__ ac, const float* __restrict__ man,
    const float* __restrict__ c1w, const float* __restrict__ c1b,
    const float* __restrict__ bn1g, const float* __restrict__ bn1b,
    const float* __restrict__ c2w, const float* __restrict__ c2b,
    const float* __restrict__ bn2g, const float* __restrict__ bn2b,
    const float* __restrict__ wih, const float* __restrict__ bih,
    float* __restrict__ gi_out)      // (B, 1521, 3)
{
    __shared__ float y1[8][NPIX + 7];
    const int b = blockIdx.x;
    const int tid = threadIdx.x;

    for (int p = tid; p < NPIX; p += 256) {
        float m = nan0(man[b * NPIX + p]);
        float a = nan0(ac[b * NPIX + p]);
        float v = nan0(ve[b * NPIX + p]);
#pragma unroll
        for (int c = 0; c < 8; ++c) {
            float val = c1w[c * 3 + 0] * m + c1w[c * 3 + 1] * a + c1w[c * 3 + 2] * v + c1b[c];
            val = val * (bn1g[c] * BN_RSQ) + bn1b[c];
            y1[c][p] = fmaxf(val, 0.f);
        }
    }
    __syncthreads();

    for (int p = tid; p < NPIX; p += 256) {
        const int h = p / WN, w = p - h * WN;
        float acc[16];
#pragma unroll
        for (int o = 0; o < 16; ++o) acc[o] = 0.f;
        for (int c = 0; c < 8; ++c) {
#pragma unroll
            for (int dy = 0; dy < 3; ++dy) {
                const int hh = h + dy - 1;
                if (hh < 0 || hh >= HN) continue;
#pragma unroll
                for (int dx = 0; dx < 3; ++dx) {
                    const int ww = w + dx - 1;
                    if (ww < 0 || ww >= WN) continue;
                    const float yv = y1[c][hh * WN + ww];
#pragma unroll
                    for (int o = 0; o < 16; ++o)
                        acc[o] = fmaf(c2w[((o * 8 + c) * 3 + dy) * 3 + dx], yv, acc[o]);
                }
            }
        }
        float gi0 = bih[0], gi1 = bih[1], gi2 = bih[2];
#pragma unroll
        for (int o = 0; o < 16; ++o) {
            const float x2 = (acc[o] + c2b[o]) * (bn2g[o] * BN_RSQ) + bn2b[o];
            gi0 = fmaf(wih[0 * 16 + o], x2, gi0);
            gi1 = fmaf(wih[1 * 16 + o], x2, gi1);
            gi2 = fmaf(wih[2 * 16 + o], x2, gi2);
        }
        const int idx = (b * NPIX + p) * 3;
        gi_out[idx + 0] = gi0;
        gi_out[idx + 1] = gi1;
        gi_out[idx + 2] = gi2;
    }
}

// ---------------------------------------------------------------------------
// K2: GRU(16->1) over rows; one thread per (b,w) sequence
// ---------------------------------------------------------------------------
__global__ __launch_bounds__(256) void gru_kernel(
    const float* __restrict__ gi, const float* __restrict__ whh, const float* __restrict__ bhh,
    float* __restrict__ enc1)   // (B, 39, 39)
{
    const int idx = blockIdx.x * 256 + threadIdx.x;
    if (idx >= NNODE) return;
    const int b = idx / WN, w = idx - (idx / WN) * WN;
    const float wh0 = whh[0], wh1 = whh[1], wh2 = whh[2];
    const float bh0 = bhh[0], bh1 = bhh[1], bh2 = bhh[2];
    float h = 0.f;
    for (int t = 0; t < HN; ++t) {
        const float* g = gi + ((size_t)b * NPIX + t * WN + w) * 3;
        const float g0 = g[0], g1 = g[1], g2 = g[2];
        const float r = sigmoid_f(g0 + h * wh0 + bh0);
        const float z = sigmoid_f(g1 + h * wh1 + bh1);
        const float n = tanh_f(g2 + r * (h * wh2 + bh2));
        h = (1.f - z) * n + z * h;
        enc1[b * NPIX + t * WN + w] = h;
    }
}

// ---------------------------------------------------------------------------
// K3: build node features xn (N, 78)
// ---------------------------------------------------------------------------
__global__ __launch_bounds__(256) void xn_kernel(
    const float* __restrict__ man, const float* __restrict__ enc1,
    const float* __restrict__ maskv, float* __restrict__ xn)
{
    const int idx = blockIdx.x * 256 + threadIdx.x;
    if (idx >= NNODE * 78) return;
    const int n = idx / 78, k = idx - n * 78;
    const int b = n / WN, w = n - b * WN;
    const float mk = maskv[b * WN + w];
    float v;
    if (k < HN) v = nan0(man[b * NPIX + k * WN + w]);
    else        v = enc1[b * NPIX + (k - HN) * WN + w];
    xn[idx] = v * mk;
}

// ---------------------------------------------------------------------------
// K4: CSR build (histogram -> scan -> scatter)
// ---------------------------------------------------------------------------
__global__ __launch_bounds__(256) void edge_hist(const int* __restrict__ ei, int* __restrict__ counts)
{
    const int e = blockIdx.x * 256 + threadIdx.x;
    if (e >= E_TOT) return;
    const int d = (e < E_RAW) ? ei[E_RAW + e] : (e - E_RAW);
    atomicAdd(&counts[d], 1);
}

__global__ __launch_bounds__(256) void scan_kernel(const int* __restrict__ counts,
                                                   int* __restrict__ offsets, int* __restrict__ cursor)
{
    __shared__ int sums[256];
    const int tid = threadIdx.x;
    const int start = tid * 20;
    const int end = min(start + 20, NNODE);
    int s = 0;
    for (int i = start; i < end; ++i) s += counts[i];
    sums[tid] = s;
    __syncthreads();
    for (int off = 1; off < 256; off <<= 1) {
        int v = (tid >= off) ? sums[tid - off] : 0;
        __syncthreads();
        sums[tid] += v;
        __syncthreads();
    }
    int run = (tid == 0) ? 0 : sums[tid - 1];
    for (int i = start; i < end; ++i) {
        offsets[i] = run;
        cursor[i] = run;
        run += counts[i];
    }
    if (tid == 255) offsets[NNODE] = run;
}

__global__ __launch_bounds__(256) void edge_scatter(const int* __restrict__ ei,
                                                    int* __restrict__ cursor, int* __restrict__ srcs)
{
    const int e = blockIdx.x * 256 + threadIdx.x;
    if (e >= E_TOT) return;
    int s, d;
    if (e < E_RAW) { s = ei[e]; d = ei[E_RAW + e]; }
    else           { s = d = e - E_RAW; }
    const int pos = atomicAdd(&cursor[d], 1);
    srcs[pos] = s;
}

// ---------------------------------------------------------------------------
// K5: tiled f32 GEMM  Y = X(M,K) @ W(J,K)^T + b, for both (Wl,Yl) and (Wr,Yr).
// Grid: (M/64, 2*J/64). blockIdx.y selects which W/Y and the j-tile.
// Inner unroll capped at 8 to bound VGPR pressure (R1 fix: unroll-32 hoisted
// all ds_reads -> 256 VGPR + scratch spills -> 795 MB HBM traffic/dispatch).
// ---------------------------------------------------------------------------
template <int K>
__global__ __launch_bounds__(256, 4) void gemm_kernel(
    const float* __restrict__ X,
    const float* __restrict__ Wl, const float* __restrict__ bl,
    const float* __restrict__ Wr, const float* __restrict__ br,
    float* __restrict__ Yl, float* __restrict__ Yr, int J)
{
    const int nyb = J >> 6;
    const int sel = (blockIdx.y >= nyb) ? 1 : 0;
    const int j0 = (blockIdx.y - sel * nyb) * 64;
    const float* __restrict__ W = sel ? Wr : Wl;
    const float* __restrict__ bias = sel ? br : bl;
    float* __restrict__ Y = sel ? Yr : Yl;

    __shared__ __align__(16) float Xs[32][68];
    __shared__ __align__(16) float Ws[32][68];

    const int m0 = blockIdx.x * 64;
    const int tid = threadIdx.x;
    const int ti = tid / 16, tj = tid & 15;
    const int lrow = tid >> 2;            // 0..63
    const int ks = (tid & 3) * 8;         // 0,8,16,24

    float acc[4][4];
#pragma unroll
    for (int i = 0; i < 4; ++i)
#pragma unroll
        for (int j = 0; j < 4; ++j) acc[i][j] = 0.f;

    for (int k0 = 0; k0 < K; k0 += 32) {
        const float* xp = X + (size_t)(m0 + lrow) * K + k0 + ks;
        const float* wp = W + (size_t)(j0 + lrow) * K + k0 + ks;
#pragma unroll
        for (int q = 0; q < 8; ++q) {
            const int k = k0 + ks + q;
            Xs[ks + q][lrow] = (k < K) ? xp[q] : 0.f;
            Ws[ks + q][lrow] = (k < K) ? wp[q] : 0.f;
        }
        __syncthreads();
#pragma unroll 8
        for (int kk = 0; kk < 32; ++kk) {
            const float4 xv = *(const float4*)&Xs[kk][ti * 4];
            const float4 wv = *(const float4*)&Ws[kk][tj * 4];
            acc[0][0] = fmaf(xv.x, wv.x, acc[0][0]);
            acc[0][1] = fmaf(xv.x, wv.y, acc[0][1]);
            acc[0][2] = fmaf(xv.x, wv.z, acc[0][2]);
            acc[0][3] = fmaf(xv.x, wv.w, acc[0][3]);
            acc[1][0] = fmaf(xv.y, wv.x, acc[1][0]);
            acc[1][1] = fmaf(xv.y, wv.y, acc[1][1]);
            acc[1][2] = fmaf(xv.y, wv.z, acc[1][2]);
            acc[1][3] = fmaf(xv.y, wv.w, acc[1][3]);
            acc[2][0] = fmaf(xv.z, wv.x, acc[2][0]);
            acc[2][1] = fmaf(xv.z, wv.y, acc[2][1]);
            acc[2][2] = fmaf(xv.z, wv.z, acc[2][2]);
            acc[2][3] = fmaf(xv.z, wv.w, acc[2][3]);
            acc[3][0] = fmaf(xv.w, wv.x, acc[3][0]);
            acc[3][1] = fmaf(xv.w, wv.y, acc[3][1]);
            acc[3][2] = fmaf(xv.w, wv.z, acc[3][2]);
            acc[3][3] = fmaf(xv.w, wv.w, acc[3][3]);
        }
        __syncthreads();
    }
#pragma unroll
    for (int i = 0; i < 4; ++i) {
        const int m = m0 + ti * 4 + i;
#pragma unroll
        for (int j = 0; j < 4; ++j) {
            const int jj = j0 + tj * 4 + j;
            Y[(size_t)m * J + jj] = acc[i][j] + bias[jj];
        }
    }
}

// ---------------------------------------------------------------------------
// K6: GATv2 layer 1 (8 heads x 64ch). One block (512 thr) per dst node.
// ---------------------------------------------------------------------------
__global__ __launch_bounds__(512) void gat1_kernel(
    const float* __restrict__ xl, const float* __restrict__ xr,
    const float* __restrict__ att, const float* __restrict__ bias,
    const int* __restrict__ offsets, const int* __restrict__ srcs,
    float* __restrict__ h1)
{
    const int n = blockIdx.x;
    const int t = threadIdx.x;
    const float xrv = xr[(size_t)n * F1 + t];
    const float attv = att[t];
    const int base = offsets[n];
    const int deg = offsets[n + 1] - base;

    float m = -1e30f, l = 0.f, acc = 0.f;
    int s = srcs[base];
    for (int i = 0; i < deg; ++i) {
        const int s_cur = s;
        if (i + 1 < deg) s = srcs[base + i + 1];
        const float xlv = xl[(size_t)s_cur * F1 + t];
        float ev = xlv + xrv;
        ev = (ev > 0.f) ? ev : 0.2f * ev;
        float part = ev * attv;
#pragma unroll
        for (int o = 32; o >= 1; o >>= 1) part += __shfl_xor(part, o, 64);
        const float logit = part;
        const float m2 = fmaxf(m, logit);
        const float sc = __expf(m - m2);
        const float w = __expf(logit - m2);
        l = l * sc + w;
        acc = acc * sc + w * xlv;
        m = m2;
    }
    float out = acc / l + bias[t];
    out = (out > 0.f) ? out : expm1f(out);   // ELU
    h1[(size_t)n * F1 + t] = out;
}

// ---------------------------------------------------------------------------
// K7: GATv2 layer 2 (1 head x 64ch). One wave per dst node, 4 nodes/block.
// ---------------------------------------------------------------------------
__global__ __launch_bounds__(256) void gat2_kernel(
    const float* __restrict__ xl, const float* __restrict__ xr,
    const float* __restrict__ att, const float* __restrict__ bias,
    const int* __restrict__ offsets, const int* __restrict__ srcs,
    float* __restrict__ out)
{
    const int wave = threadIdx.x >> 6;
    const int lane = threadIdx.x & 63;
    const int n = blockIdx.x * 4 + wave;
    if (n >= NNODE) return;
    const float xrv = xr[(size_t)n * F2 + lane];
    const float attv = att[lane];
    const int base = offsets[n];
    const int deg = offsets[n + 1] - base;

    float m = -1e30f, l = 0.f, acc = 0.f;
    int s = srcs[base];
    for (int i = 0; i < deg; ++i) {
        const int s_cur = s;
        if (i + 1 < deg) s = srcs[base + i + 1];
        const float xlv = xl[(size_t)s_cur * F2 + lane];
        float ev = xlv + xrv;
        ev = (ev > 0.f) ? ev : 0.2f * ev;
        float part = ev * attv;
#pragma unroll
        for (int o = 32; o >= 1; o >>= 1) part += __shfl_xor(part, o, 64);
        const float logit = part;
        const float m2 = fmaxf(m, logit);
        const float sc = __expf(m - m2);
        const float w = __expf(logit - m2);
        l = l * sc + w;
        acc = acc * sc + w * xlv;
        m = m2;
    }
    out[(size_t)n * F2 + lane] = acc / l + bias[lane];
}

// ---------------------------------------------------------------------------
extern "C" void kernel_launch(void* const* d_in, const int* in_sizes, int n_in,
                              void* d_out, int out_size, void* d_ws, size_t ws_size,
                              hipStream_t stream)
{
    const int*   ei    = (const int*)d_in[0];
    const float* ve    = (const float*)d_in[1];
    const float* ac    = (const float*)d_in[2];
    const float* man   = (const float*)d_in[3];
    const float* maskv = (const float*)d_in[4];
    const float* c1w   = (const float*)d_in[6];
    const float* c1b   = (const float*)d_in[7];
    const float* bn1g  = (const float*)d_in[8];
    const float* bn1b  = (const float*)d_in[9];
    const float* c2w   = (const float*)d_in[10];
    const float* c2b   = (const float*)d_in[11];
    const float* bn2g  = (const float*)d_in[12];
    const float* bn2b  = (const float*)d_in[13];
    const float* wih   = (const float*)d_in[14];
    const float* whh   = (const float*)d_in[15];
    const float* bih   = (const float*)d_in[16];
    const float* bhh   = (const float*)d_in[17];
    const float* g1wl  = (const float*)d_in[18];
    const float* g1bl  = (const float*)d_in[19];
    const float* g1wr  = (const float*)d_in[20];
    const float* g1br  = (const float*)d_in[21];
    const float* g1att = (const float*)d_in[22];
    const float* g1bias= (const float*)d_in[23];
    const float* g2wl  = (const float*)d_in[24];
    const float* g2bl  = (const float*)d_in[25];
    const float* g2wr  = (const float*)d_in[26];
    const float* g2br  = (const float*)d_in[27];
    const float* g2att = (const float*)d_in[28];
    const float* g2bias= (const float*)d_in[29];
    float* outp = (float*)d_out;

    // workspace layout (floats)
    float* ws   = (float*)d_ws;
    float* gi   = ws;                       // 584064
    float* enc1 = gi   + 584064;            // 194688
    float* xn   = enc1 + 194688;            // 389376
    float* xl1  = xn   + 389376;            // 2555904
    float* xr1  = xl1  + 2555904;           // 2555904
    float* h1   = xr1  + 2555904;           // 2555904
    float* xl2  = h1   + 2555904;           // 319488
    float* xr2  = xl2  + 319488;            // 319488
    int* counts  = (int*)(xr2 + 319488);    // 4992
    int* offsets = counts + NNODE;          // 4993
    int* cursor  = offsets + NNODE + 1;     // 4992
    int* srcs    = cursor + NNODE;          // 205056

    hipMemsetAsync(counts, 0, NNODE * sizeof(int), stream);

    conv_kernel<<<NBATCH, 256, 0, stream>>>(ve, ac, man, c1w, c1b, bn1g, bn1b,
                                            c2w, c2b, bn2g, bn2b, wih, bih, gi);
    gru_kernel<<<(NNODE + 255) / 256, 256, 0, stream>>>(gi, whh, bhh, enc1);
    xn_kernel<<<(NNODE * 78 + 255) / 256, 256, 0, stream>>>(man, enc1, maskv, xn);

    edge_hist<<<(E_TOT + 255) / 256, 256, 0, stream>>>(ei, counts);
    scan_kernel<<<1, 256, 0, stream>>>(counts, offsets, cursor);
    edge_scatter<<<(E_TOT + 255) / 256, 256, 0, stream>>>(ei, cursor, srcs);

    gemm_kernel<78><<<dim3(NNODE / 64, 2 * (F1 / 64)), 256, 0, stream>>>(
        xn, g1wl, g1bl, g1wr, g1br, xl1, xr1, F1);

    gat1_kernel<<<NNODE, 512, 0, stream>>>(xl1, xr1, g1att, g1bias, offsets, srcs, h1);

    gemm_kernel<512><<<dim3(NNODE / 64, 2 * (F2 / 64)), 256, 0, stream>>>(
        h1, g2wl, g2bl, g2wr, g2br, xl2, xr2, F2);

    gat2_kernel<<<(NNODE + 3) / 4, 256, 0, stream>>>(xl2, xr2, g2att, g2bias, offsets, srcs, outp);
}